// Round 1
// baseline (494.022 us; speedup 1.0000x reference)
//
#include <hip/hip_runtime.h>

#define S_LEN 2048
#define NHEAD 16
#define HDIM 64
#define EMB 1024

typedef short v8s __attribute__((ext_vector_type(8)));
typedef float v4f __attribute__((ext_vector_type(4)));

__device__ __forceinline__ unsigned short f2bf(float f) {
    union { float f; unsigned u; } v; v.f = f;
    unsigned r = v.u + 0x7FFFu + ((v.u >> 16) & 1u);
    return (unsigned short)(r >> 16);
}
__device__ __forceinline__ float bf2f(unsigned h) {
    union { unsigned u; float f; } v; v.u = h << 16;
    return v.f;
}

// ---------------------------------------------------------------------------
// K1: fused per-head projections. One block per (b,s) row.
// Writes Qp/Kp/Vp bf16 in [b][h][s][d] (head-major) layout.
// ---------------------------------------------------------------------------
__global__ __launch_bounds__(256) void k_proj(
    const float* __restrict__ q, const float* __restrict__ k, const float* __restrict__ v,
    const float* __restrict__ Wq, const float* __restrict__ Wk, const float* __restrict__ Wv,
    unsigned short* __restrict__ Qp, unsigned short* __restrict__ Kp, unsigned short* __restrict__ Vp)
{
    __shared__ float X[3][EMB];
    __shared__ float Wt[3][64 * 64];   // W transposed: Wt[d][e] = W[e][d]
    const int t = threadIdx.x;
    const int bs = blockIdx.x;
    const int b = bs >> 11, s = bs & 2047;
    const float* xin[3] = { q + (size_t)bs * EMB, k + (size_t)bs * EMB, v + (size_t)bs * EMB };
    const float* win[3] = { Wq, Wk, Wv };
    #pragma unroll
    for (int m = 0; m < 3; ++m) {
        ((float4*)X[m])[t] = ((const float4*)xin[m])[t];
        #pragma unroll
        for (int i = 0; i < 4; ++i) {
            float4 wv = ((const float4*)win[m])[t * 4 + i];
            int f = t * 16 + i * 4;
            Wt[m][((f + 0) & 63) * 64 + ((f + 0) >> 6)] = wv.x;
            Wt[m][((f + 1) & 63) * 64 + ((f + 1) >> 6)] = wv.y;
            Wt[m][((f + 2) & 63) * 64 + ((f + 2) >> 6)] = wv.z;
            Wt[m][((f + 3) & 63) * 64 + ((f + 3) >> 6)] = wv.w;
        }
    }
    __syncthreads();
    const int wave = t >> 6, lane = t & 63;
    #pragma unroll
    for (int j = 0; j < 4; ++j) {
        const int h = wave + j * 4;
        float a0 = 0.f, a1 = 0.f, a2 = 0.f;
        #pragma unroll 8
        for (int d = 0; d < 64; ++d) {
            a0 += X[0][h * 64 + d] * Wt[0][d * 64 + lane];
            a1 += X[1][h * 64 + d] * Wt[1][d * 64 + lane];
            a2 += X[2][h * 64 + d] * Wt[2][d * 64 + lane];
        }
        size_t o = ((size_t)(b * NHEAD + h) * S_LEN + s) * HDIM + lane;
        Qp[o] = f2bf(a0); Kp[o] = f2bf(a1); Vp[o] = f2bf(a2);
    }
}

// ---------------------------------------------------------------------------
// K1b: Vp [b][h][s][d] -> Vt [b][h][d][s] (for contiguous PV B-fragments)
// ---------------------------------------------------------------------------
__global__ __launch_bounds__(256) void k_transpose(
    const unsigned short* __restrict__ Vp, unsigned short* __restrict__ Vt)
{
    __shared__ unsigned short T[128 * 72];   // rows: s (128), stride 72 bf16 (pad)
    const int t = threadIdx.x;
    const int bh = blockIdx.y;               // b*16+h, 0..31
    const int st = blockIdx.x;               // s-tile of 128, 0..15
    const unsigned short* src = Vp + ((size_t)bh * S_LEN + st * 128) * HDIM;
    #pragma unroll
    for (int i = 0; i < 4; ++i) {
        int idx = (t + i * 256) * 8;         // element in 128x64 tile
        int s = idx >> 6, d = idx & 63;
        *((int4*)&T[s * 72 + d]) = ((const int4*)src)[t + i * 256];
    }
    __syncthreads();
    unsigned short* dst = Vt + (size_t)bh * HDIM * S_LEN + st * 128;
    #pragma unroll
    for (int i = 0; i < 4; ++i) {
        int flat = t + i * 256;              // 0..1023
        int d = flat >> 4, sc = flat & 15;
        unsigned short tmp[8];
        #pragma unroll
        for (int jj = 0; jj < 8; ++jj) tmp[jj] = T[(sc * 8 + jj) * 72 + d];
        *((int4*)&dst[(size_t)d * S_LEN + sc * 8]) = *(int4*)tmp;
    }
}

// ---------------------------------------------------------------------------
// K1c: W_fc fp32 -> bf16
// ---------------------------------------------------------------------------
__global__ __launch_bounds__(256) void k_cvtw(
    const float* __restrict__ W, unsigned short* __restrict__ Wb)
{
    const int i = (blockIdx.x * 256 + threadIdx.x) * 4;
    float4 wv = *(const float4*)(W + i);
    uint2 pk;
    pk.x = (unsigned)f2bf(wv.x) | ((unsigned)f2bf(wv.y) << 16);
    pk.y = (unsigned)f2bf(wv.z) | ((unsigned)f2bf(wv.w) << 16);
    *(uint2*)(Wb + i) = pk;
}

// ---------------------------------------------------------------------------
// K2: pass 1 — Zr[b,q,k] = 1 / sum_h exp(S_h(q,k)/32), stored bf16 in MFMA
// C-fragment lane order: Zr[(b*128+qt)*128+kt][lane] = {r0,r1,r2,r3} packed.
// One wave handles one 16x16 (q,k) patch across ALL 16 heads -> head-sum is
// register-local (no LDS, no barriers).
// ---------------------------------------------------------------------------
__global__ __launch_bounds__(256, 2) void k_z(
    const unsigned short* __restrict__ Qp, const unsigned short* __restrict__ Kp,
    uint2* __restrict__ Zr)
{
    const int t = threadIdx.x, wave = t >> 6, lane = t & 63;
    const int l15 = lane & 15, l4 = lane >> 4;
    const int b = blockIdx.z;
    const int qt = blockIdx.y * 4 + wave;    // q-tile-of-16 index, 0..127
    v8s aq[16][2];
    #pragma unroll
    for (int h = 0; h < 16; ++h)
        #pragma unroll
        for (int c2 = 0; c2 < 2; ++c2)
            aq[h][c2] = *(const v8s*)(Qp + ((size_t)(b * NHEAD + h) * S_LEN + qt * 16 + l15) * HDIM + c2 * 32 + l4 * 8);
    for (int step = 0; step < 8; ++step) {
        const int kt = blockIdx.x * 8 + step;   // k-tile-of-16 index, 0..127
        v4f c[16];
        #pragma unroll
        for (int h = 0; h < 16; ++h) {
            const unsigned short* kb = Kp + ((size_t)(b * NHEAD + h) * S_LEN + kt * 16 + l15) * HDIM + l4 * 8;
            v8s b0 = *(const v8s*)kb;
            v8s b1 = *(const v8s*)(kb + 32);
            v4f acc = (v4f){0.f, 0.f, 0.f, 0.f};
            acc = __builtin_amdgcn_mfma_f32_16x16x32_bf16(aq[h][0], b0, acc, 0, 0, 0);
            acc = __builtin_amdgcn_mfma_f32_16x16x32_bf16(aq[h][1], b1, acc, 0, 0, 0);
            c[h] = acc;
        }
        unsigned o4[4];
        #pragma unroll
        for (int r = 0; r < 4; ++r) {
            float z = 0.f;
            #pragma unroll
            for (int h = 0; h < 16; ++h) z += __expf(c[h][r] * 0.03125f);
            o4[r] = f2bf(__builtin_amdgcn_rcpf(z));
        }
        uint2 zo; zo.x = o4[0] | (o4[1] << 16); zo.y = o4[2] | (o4[3] << 16);
        Zr[((size_t)(b * 128 + qt) * 128 + kt) * 64 + lane] = zo;
    }
}

// ---------------------------------------------------------------------------
// K3: pass 2 — AO[b,s,h*64+d] = sum_k exp(S/32)*Zr * V. Block: 4 heads x 2
// k-halves (8 waves), qT=64, full k. P goes C-layout -> A-layout via a
// per-wave private LDS buffer (pad-40 rows: 16B-aligned + conflict-free).
// ---------------------------------------------------------------------------
__global__ __launch_bounds__(512, 2) void k_attn(
    const unsigned short* __restrict__ Qp, const unsigned short* __restrict__ Kp,
    const unsigned short* __restrict__ Vt, const uint2* __restrict__ Zr,
    unsigned short* __restrict__ AO)
{
    __shared__ unsigned short Pl[8][64 * 40];   // 40 KiB; reused as merge buffer
    const int t = threadIdx.x, wave = t >> 6, lane = t & 63;
    const int l15 = lane & 15, l4 = lane >> 4;
    const int b = blockIdx.z, hg = blockIdx.y;
    const int h = hg * 4 + (wave & 3);
    const int khalf = wave >> 2;
    const int q0 = blockIdx.x * 64;
    const unsigned short* qh = Qp + (size_t)(b * NHEAD + h) * S_LEN * HDIM;
    const unsigned short* kh = Kp + (size_t)(b * NHEAD + h) * S_LEN * HDIM;
    const unsigned short* vh = Vt + (size_t)(b * NHEAD + h) * HDIM * S_LEN;

    v8s aq[4][2];
    #pragma unroll
    for (int qs = 0; qs < 4; ++qs)
        #pragma unroll
        for (int c2 = 0; c2 < 2; ++c2)
            aq[qs][c2] = *(const v8s*)(qh + (size_t)(q0 + qs * 16 + l15) * HDIM + c2 * 32 + l4 * 8);

    v4f o[4][4];
    #pragma unroll
    for (int i = 0; i < 4; ++i)
        #pragma unroll
        for (int jj = 0; jj < 4; ++jj)
            o[i][jj] = (v4f){0.f, 0.f, 0.f, 0.f};

    unsigned short* pl = &Pl[wave][0];
    const int kbeg = khalf * 1024;
    for (int kk = kbeg; kk < kbeg + 1024; kk += 32) {
        v8s bk[2][2];
        #pragma unroll
        for (int ks = 0; ks < 2; ++ks)
            #pragma unroll
            for (int c2 = 0; c2 < 2; ++c2)
                bk[ks][c2] = *(const v8s*)(kh + (size_t)(kk + ks * 16 + l15) * HDIM + c2 * 32 + l4 * 8);
        #pragma unroll
        for (int qs = 0; qs < 4; ++qs) {
            const int qt = blockIdx.x * 4 + qs;
            #pragma unroll
            for (int ks = 0; ks < 2; ++ks) {
                v4f sf = (v4f){0.f, 0.f, 0.f, 0.f};
                sf = __builtin_amdgcn_mfma_f32_16x16x32_bf16(aq[qs][0], bk[ks][0], sf, 0, 0, 0);
                sf = __builtin_amdgcn_mfma_f32_16x16x32_bf16(aq[qs][1], bk[ks][1], sf, 0, 0, 0);
                const int kt = (kk >> 4) + ks;
                uint2 zv = Zr[((size_t)(b * 128 + qt) * 128 + kt) * 64 + lane];
                const float zr0 = bf2f(zv.x & 0xFFFFu), zr1 = bf2f(zv.x >> 16);
                const float zr2 = bf2f(zv.y & 0xFFFFu), zr3 = bf2f(zv.y >> 16);
                pl[(qs * 16 + l4 * 4 + 0) * 40 + ks * 16 + l15] = f2bf(__expf(sf[0] * 0.03125f) * zr0);
                pl[(qs * 16 + l4 * 4 + 1) * 40 + ks * 16 + l15] = f2bf(__expf(sf[1] * 0.03125f) * zr1);
                pl[(qs * 16 + l4 * 4 + 2) * 40 + ks * 16 + l15] = f2bf(__expf(sf[2] * 0.03125f) * zr2);
                pl[(qs * 16 + l4 * 4 + 3) * 40 + ks * 16 + l15] = f2bf(__expf(sf[3] * 0.03125f) * zr3);
            }
        }
        #pragma unroll
        for (int qs = 0; qs < 4; ++qs) {
            v8s ap = *(const v8s*)&pl[(qs * 16 + l15) * 40 + l4 * 8];
            #pragma unroll
            for (int ds = 0; ds < 4; ++ds) {
                v8s bv = *(const v8s*)(vh + (size_t)(ds * 16 + l15) * S_LEN + kk + l4 * 8);
                o[qs][ds] = __builtin_amdgcn_mfma_f32_16x16x32_bf16(ap, bv, o[qs][ds], 0, 0, 0);
            }
        }
    }

    // merge the two k-halves: waves 4..7 hand their partials to waves 0..3
    float* mg = (float*)&Pl[0][0];   // 2 waves * 64 lanes * 68 floats = 34816 B
    #pragma unroll
    for (int round = 0; round < 2; ++round) {
        __syncthreads();
        const int srcw = 4 + round * 2;
        if (wave == srcw || wave == srcw + 1) {
            float* dst = mg + (size_t)((wave - srcw) * 64 + lane) * 68;
            #pragma unroll
            for (int qs = 0; qs < 4; ++qs)
                #pragma unroll
                for (int ds = 0; ds < 4; ++ds)
                    #pragma unroll
                    for (int r = 0; r < 4; ++r)
                        dst[(qs * 4 + ds) * 4 + r] = o[qs][ds][r];
        }
        __syncthreads();
        if (wave == round * 2 || wave == round * 2 + 1) {
            const float* src2 = mg + (size_t)((wave - round * 2) * 64 + lane) * 68;
            #pragma unroll
            for (int qs = 0; qs < 4; ++qs)
                #pragma unroll
                for (int ds = 0; ds < 4; ++ds)
                    #pragma unroll
                    for (int r = 0; r < 4; ++r)
                        o[qs][ds][r] += src2[(qs * 4 + ds) * 4 + r];
        }
    }
    if (wave < 4) {
        #pragma unroll
        for (int qs = 0; qs < 4; ++qs)
            #pragma unroll
            for (int ds = 0; ds < 4; ++ds)
                #pragma unroll
                for (int r = 0; r < 4; ++r)
                    AO[((size_t)b * S_LEN + q0 + qs * 16 + l4 * 4 + r) * EMB + h * 64 + ds * 16 + l15] =
                        f2bf(o[qs][ds][r]);
    }
}

// ---------------------------------------------------------------------------
// K4: out = AO @ W_fc^T + b_fc   (M=4096, N=1024, K=1024), fp32 out
// ---------------------------------------------------------------------------
__global__ __launch_bounds__(256) void k_fc(
    const unsigned short* __restrict__ AO, const unsigned short* __restrict__ Wb,
    const float* __restrict__ bias, float* __restrict__ out)
{
    const int t = threadIdx.x, wave = t >> 6, lane = t & 63;
    const int l15 = lane & 15, l4 = lane >> 4;
    const int m0 = blockIdx.x * 64 + wave * 16;
    const int n0 = blockIdx.y * 64;
    v4f c[4];
    #pragma unroll
    for (int i = 0; i < 4; ++i) c[i] = (v4f){0.f, 0.f, 0.f, 0.f};
    for (int k = 0; k < EMB; k += 32) {
        v8s a = *(const v8s*)(AO + (size_t)(m0 + l15) * EMB + k + l4 * 8);
        #pragma unroll
        for (int ns = 0; ns < 4; ++ns) {
            v8s bw = *(const v8s*)(Wb + (size_t)(n0 + ns * 16 + l15) * EMB + k + l4 * 8);
            c[ns] = __builtin_amdgcn_mfma_f32_16x16x32_bf16(a, bw, c[ns], 0, 0, 0);
        }
    }
    #pragma unroll
    for (int ns = 0; ns < 4; ++ns) {
        const float bv = bias[n0 + ns * 16 + l15];
        #pragma unroll
        for (int r = 0; r < 4; ++r)
            out[(size_t)(m0 + l4 * 4 + r) * EMB + n0 + ns * 16 + l15] = c[ns][r] + bv;
    }
}

extern "C" void kernel_launch(void* const* d_in, const int* in_sizes, int n_in,
                              void* d_out, int out_size, void* d_ws, size_t ws_size,
                              hipStream_t stream)
{
    (void)in_sizes; (void)n_in; (void)out_size; (void)ws_size;
    const float* q   = (const float*)d_in[0];
    const float* k   = (const float*)d_in[1];
    const float* v   = (const float*)d_in[2];
    const float* Wq  = (const float*)d_in[3];
    const float* Wk  = (const float*)d_in[4];
    const float* Wv  = (const float*)d_in[5];
    const float* Wfc = (const float*)d_in[6];
    const float* bfc = (const float*)d_in[7];

    char* w = (char*)d_ws;
    unsigned short* Qp = (unsigned short*)(w);                      //  8 MiB
    unsigned short* Kp = (unsigned short*)(w + (8u  << 20));        //  8 MiB
    unsigned short* Vp = (unsigned short*)(w + (16u << 20));        //  8 MiB
    unsigned short* Vt = (unsigned short*)(w + (24u << 20));        //  8 MiB
    unsigned short* AO = (unsigned short*)(w + (32u << 20));        //  8 MiB
    uint2*          Zr = (uint2*)         (w + (40u << 20));        // 16 MiB
    unsigned short* Wb = (unsigned short*)(w + (56u << 20));        //  2 MiB -> 58 MiB total

    k_proj     <<<dim3(4096),       dim3(256), 0, stream>>>(q, k, v, Wq, Wk, Wv, Qp, Kp, Vp);
    k_transpose<<<dim3(16, 32),     dim3(256), 0, stream>>>(Vp, Vt);
    k_cvtw     <<<dim3(1024),       dim3(256), 0, stream>>>(Wfc, Wb);
    k_z        <<<dim3(16, 32, 2),  dim3(256), 0, stream>>>(Qp, Kp, Zr);
    k_attn     <<<dim3(32, 4, 2),   dim3(512), 0, stream>>>(Qp, Kp, Vt, (const uint2*)Zr, AO);
    k_fc       <<<dim3(64, 16),     dim3(256), 0, stream>>>(AO, Wb, bfc, (float*)d_out);
}

// Round 4
// 398.692 us; speedup vs baseline: 1.2391x; 1.2391x over previous
//
#include <hip/hip_runtime.h>

#define S_LEN 2048
#define NHEAD 16
#define HDIM 64
#define EMB 1024

typedef short v8s __attribute__((ext_vector_type(8)));
typedef float v4f __attribute__((ext_vector_type(4)));

__device__ __forceinline__ unsigned short f2bf(float f) {
    union { float f; unsigned u; } v; v.f = f;
    unsigned r = v.u + 0x7FFFu + ((v.u >> 16) & 1u);
    return (unsigned short)(r >> 16);
}
__device__ __forceinline__ float bf2f(unsigned h) {
    union { unsigned u; float f; } v; v.u = h << 16;
    return v.f;
}
__device__ __forceinline__ float bflo(unsigned u) {
    union { unsigned u; float f; } v; v.u = u << 16; return v.f;
}
__device__ __forceinline__ float bfhi(unsigned u) {
    union { unsigned u; float f; } v; v.u = u & 0xFFFF0000u; return v.f;
}
__device__ __forceinline__ unsigned pack2(float lo, float hi) {
    return (unsigned)f2bf(lo) | ((unsigned)f2bf(hi) << 16);
}

// ---------------------------------------------------------------------------
// K1: fused per-head projections. One block per (b,s) row.
// Writes Qp/Kp/Vp bf16 in [b][h][s][d] (head-major) layout.
// ---------------------------------------------------------------------------
__global__ __launch_bounds__(256) void k_proj(
    const float* __restrict__ q, const float* __restrict__ k, const float* __restrict__ v,
    const float* __restrict__ Wq, const float* __restrict__ Wk, const float* __restrict__ Wv,
    unsigned short* __restrict__ Qp, unsigned short* __restrict__ Kp, unsigned short* __restrict__ Vp)
{
    __shared__ float X[3][EMB];
    __shared__ float Wt[3][64 * 64];   // W transposed: Wt[d][e] = W[e][d]
    const int t = threadIdx.x;
    const int bs = blockIdx.x;
    const int b = bs >> 11, s = bs & 2047;
    const float* xin[3] = { q + (size_t)bs * EMB, k + (size_t)bs * EMB, v + (size_t)bs * EMB };
    const float* win[3] = { Wq, Wk, Wv };
    #pragma unroll
    for (int m = 0; m < 3; ++m) {
        ((float4*)X[m])[t] = ((const float4*)xin[m])[t];
        #pragma unroll
        for (int i = 0; i < 4; ++i) {
            float4 wv = ((const float4*)win[m])[t * 4 + i];
            int f = t * 16 + i * 4;
            Wt[m][((f + 0) & 63) * 64 + ((f + 0) >> 6)] = wv.x;
            Wt[m][((f + 1) & 63) * 64 + ((f + 1) >> 6)] = wv.y;
            Wt[m][((f + 2) & 63) * 64 + ((f + 2) >> 6)] = wv.z;
            Wt[m][((f + 3) & 63) * 64 + ((f + 3) >> 6)] = wv.w;
        }
    }
    __syncthreads();
    const int wave = t >> 6, lane = t & 63;
    #pragma unroll
    for (int j = 0; j < 4; ++j) {
        const int h = wave + j * 4;
        float a0 = 0.f, a1 = 0.f, a2 = 0.f;
        #pragma unroll 8
        for (int d = 0; d < 64; ++d) {
            a0 += X[0][h * 64 + d] * Wt[0][d * 64 + lane];
            a1 += X[1][h * 64 + d] * Wt[1][d * 64 + lane];
            a2 += X[2][h * 64 + d] * Wt[2][d * 64 + lane];
        }
        size_t o = ((size_t)(b * NHEAD + h) * S_LEN + s) * HDIM + lane;
        Qp[o] = f2bf(a0); Kp[o] = f2bf(a1); Vp[o] = f2bf(a2);
    }
}

// ---------------------------------------------------------------------------
// K1b: Vp [b][h][s][d] -> Vt [b][h][d][s] (for contiguous PV B-fragments)
// ---------------------------------------------------------------------------
__global__ __launch_bounds__(256) void k_transpose(
    const unsigned short* __restrict__ Vp, unsigned short* __restrict__ Vt)
{
    __shared__ unsigned short T[128 * 72];
    const int t = threadIdx.x;
    const int bh = blockIdx.y;               // b*16+h, 0..31
    const int st = blockIdx.x;               // s-tile of 128, 0..15
    const unsigned short* src = Vp + ((size_t)bh * S_LEN + st * 128) * HDIM;
    #pragma unroll
    for (int i = 0; i < 4; ++i) {
        int idx = (t + i * 256) * 8;
        int s = idx >> 6, d = idx & 63;
        *((int4*)&T[s * 72 + d]) = ((const int4*)src)[t + i * 256];
    }
    __syncthreads();
    unsigned short* dst = Vt + (size_t)bh * HDIM * S_LEN + st * 128;
    #pragma unroll
    for (int i = 0; i < 4; ++i) {
        int flat = t + i * 256;
        int d = flat >> 4, sc = flat & 15;
        unsigned short tmp[8];
        #pragma unroll
        for (int jj = 0; jj < 8; ++jj) tmp[jj] = T[(sc * 8 + jj) * 72 + d];
        *((int4*)&dst[(size_t)d * S_LEN + sc * 8]) = *(int4*)tmp;
    }
}

// ---------------------------------------------------------------------------
// K1c: W_fc fp32 -> bf16
// ---------------------------------------------------------------------------
__global__ __launch_bounds__(256) void k_cvtw(
    const float* __restrict__ W, unsigned short* __restrict__ Wb)
{
    const int i = (blockIdx.x * 256 + threadIdx.x) * 4;
    float4 wv = *(const float4*)(W + i);
    uint2 pk;
    pk.x = pack2(wv.x, wv.y);
    pk.y = pack2(wv.z, wv.w);
    *(uint2*)(Wb + i) = pk;
}

// ---------------------------------------------------------------------------
// K2: fused attention. One block = all 16 heads (wave w = head w) x 32 q rows
// x 1024-wide k-half. Per 64-wide k-chunk: S via MFMA -> exp to LDS (bf16,
// double-buffered) -> all-thread Z-reduce over heads -> normalize P from LDS
// in A-frag order -> PV MFMA. Partial O (one per k-half) to global bf16.
// Grid (64 qtiles, 2 khalf, 2 b) = 256 blocks = 1/CU, 16 waves/CU.
// ---------------------------------------------------------------------------
__global__ __launch_bounds__(1024, 4) void k_fattn(
    const unsigned short* __restrict__ Qp, const unsigned short* __restrict__ Kp,
    const unsigned short* __restrict__ Vt, unsigned short* __restrict__ Op)
{
    __shared__ unsigned short Pex[2][16][32][72];   // 144 KiB (double buffer)
    __shared__ float Zrs[32][68];                   // 8.5 KiB
    const int t = threadIdx.x, wave = t >> 6, lane = t & 63;
    const int l15 = lane & 15, l4 = lane >> 4;
    const int h = wave;
    const int q0 = blockIdx.x * 32;
    const int khalf = blockIdx.y;
    const int b = blockIdx.z;
    const unsigned short* qh = Qp + (size_t)(b * NHEAD + h) * S_LEN * HDIM;
    const unsigned short* kh = Kp + (size_t)(b * NHEAD + h) * S_LEN * HDIM;
    const unsigned short* vh = Vt + (size_t)(b * NHEAD + h) * HDIM * S_LEN;

    v8s aq[2][2];
    #pragma unroll
    for (int qs = 0; qs < 2; ++qs)
        #pragma unroll
        for (int c2 = 0; c2 < 2; ++c2)
            aq[qs][c2] = *(const v8s*)(qh + (size_t)(q0 + qs * 16 + l15) * HDIM + c2 * 32 + l4 * 8);

    v4f o[2][4];
    #pragma unroll
    for (int qs = 0; qs < 2; ++qs)
        #pragma unroll
        for (int ds = 0; ds < 4; ++ds)
            o[qs][ds] = (v4f){0.f, 0.f, 0.f, 0.f};

    const int zq = t >> 5;         // 0..31: q row for Z-reduce
    const int zk = (t & 31) * 2;   // 0..62: k pair for Z-reduce

    for (int c = 0; c < 16; ++c) {
        const int kk0 = khalf * 1024 + c * 64;
        const int buf = c & 1;
        // ---- phase 1: S = Q K^T, exp to LDS ----
        #pragma unroll
        for (int ks = 0; ks < 4; ++ks) {
            const unsigned short* kb = kh + (size_t)(kk0 + ks * 16 + l15) * HDIM + l4 * 8;
            v8s b0 = *(const v8s*)kb;
            v8s b1 = *(const v8s*)(kb + 32);
            #pragma unroll
            for (int qs = 0; qs < 2; ++qs) {
                v4f sf = (v4f){0.f, 0.f, 0.f, 0.f};
                sf = __builtin_amdgcn_mfma_f32_16x16x32_bf16(aq[qs][0], b0, sf, 0, 0, 0);
                sf = __builtin_amdgcn_mfma_f32_16x16x32_bf16(aq[qs][1], b1, sf, 0, 0, 0);
                #pragma unroll
                for (int r = 0; r < 4; ++r)
                    Pex[buf][h][qs * 16 + l4 * 4 + r][ks * 16 + l15] =
                        f2bf(__expf(sf[r] * 0.03125f));
            }
        }
        __syncthreads();
        // ---- phase 2: Z over heads; Zr = 1/Z ----
        {
            float z0 = 0.f, z1 = 0.f;
            #pragma unroll
            for (int hh = 0; hh < 16; ++hh) {
                unsigned u = *(const unsigned*)&Pex[buf][hh][zq][zk];
                z0 += bflo(u); z1 += bfhi(u);
            }
            float2 zr;
            zr.x = __builtin_amdgcn_rcpf(z0);
            zr.y = __builtin_amdgcn_rcpf(z1);
            *(float2*)&Zrs[zq][zk] = zr;
        }
        __syncthreads();
        // ---- phase 3: normalize P (A-frag order) + PV MFMA ----
        #pragma unroll
        for (int kq = 0; kq < 2; ++kq) {
            v8s bv[4];
            #pragma unroll
            for (int ds = 0; ds < 4; ++ds)
                bv[ds] = *(const v8s*)(vh + (size_t)(ds * 16 + l15) * S_LEN + kk0 + kq * 32 + l4 * 8);
            #pragma unroll
            for (int qs = 0; qs < 2; ++qs) {
                uint4 pu = *(const uint4*)&Pex[buf][h][qs * 16 + l15][kq * 32 + l4 * 8];
                float4 za = *(const float4*)&Zrs[qs * 16 + l15][kq * 32 + l4 * 8];
                float4 zb = *(const float4*)&Zrs[qs * 16 + l15][kq * 32 + l4 * 8 + 4];
                unsigned pw[4];
                pw[0] = pack2(bflo(pu.x) * za.x, bfhi(pu.x) * za.y);
                pw[1] = pack2(bflo(pu.y) * za.z, bfhi(pu.y) * za.w);
                pw[2] = pack2(bflo(pu.z) * zb.x, bfhi(pu.z) * zb.y);
                pw[3] = pack2(bflo(pu.w) * zb.z, bfhi(pu.w) * zb.w);
                v8s pn;
                ((unsigned*)&pn)[0] = pw[0]; ((unsigned*)&pn)[1] = pw[1];
                ((unsigned*)&pn)[2] = pw[2]; ((unsigned*)&pn)[3] = pw[3];
                #pragma unroll
                for (int ds = 0; ds < 4; ++ds)
                    o[qs][ds] = __builtin_amdgcn_mfma_f32_16x16x32_bf16(pn, bv[ds], o[qs][ds], 0, 0, 0);
            }
        }
        // next phase-1 writes the other Pex buffer; Zrs/Pex[buf] rewrites are
        // guarded by the two barriers inside the next iteration.
    }

    // partial O for this k-half, bf16, layout [khalf][b][s][e]
    unsigned short* op = Op + ((size_t)(khalf * 2 + b) * S_LEN) * EMB;
    #pragma unroll
    for (int qs = 0; qs < 2; ++qs)
        #pragma unroll
        for (int ds = 0; ds < 4; ++ds)
            #pragma unroll
            for (int r = 0; r < 4; ++r)
                op[(size_t)(q0 + qs * 16 + l4 * 4 + r) * EMB + h * 64 + ds * 16 + l15] =
                    f2bf(o[qs][ds][r]);
}

// ---------------------------------------------------------------------------
// K2b: merge the two k-half partials -> AO bf16
// ---------------------------------------------------------------------------
__global__ __launch_bounds__(256) void k_merge(
    const unsigned short* __restrict__ Op, unsigned short* __restrict__ AO)
{
    const size_t i = ((size_t)blockIdx.x * 256 + threadIdx.x) * 8;
    uint4 a = *(const uint4*)(Op + i);
    uint4 bq = *(const uint4*)(Op + (size_t)2 * S_LEN * EMB + i);
    uint4 r;
    r.x = pack2(bflo(a.x) + bflo(bq.x), bfhi(a.x) + bfhi(bq.x));
    r.y = pack2(bflo(a.y) + bflo(bq.y), bfhi(a.y) + bfhi(bq.y));
    r.z = pack2(bflo(a.z) + bflo(bq.z), bfhi(a.z) + bfhi(bq.z));
    r.w = pack2(bflo(a.w) + bflo(bq.w), bfhi(a.w) + bfhi(bq.w));
    *(uint4*)(AO + i) = r;
}

// ---------------------------------------------------------------------------
// K4: out = AO @ W_fc^T + b_fc   (M=4096, N=1024, K=1024), fp32 out
// ---------------------------------------------------------------------------
__global__ __launch_bounds__(256) void k_fc(
    const unsigned short* __restrict__ AO, const unsigned short* __restrict__ Wb,
    const float* __restrict__ bias, float* __restrict__ out)
{
    const int t = threadIdx.x, wave = t >> 6, lane = t & 63;
    const int l15 = lane & 15, l4 = lane >> 4;
    const int m0 = blockIdx.x * 64 + wave * 16;
    const int n0 = blockIdx.y * 64;
    v4f c[4];
    #pragma unroll
    for (int i = 0; i < 4; ++i) c[i] = (v4f){0.f, 0.f, 0.f, 0.f};
    for (int k = 0; k < EMB; k += 32) {
        v8s a = *(const v8s*)(AO + (size_t)(m0 + l15) * EMB + k + l4 * 8);
        #pragma unroll
        for (int ns = 0; ns < 4; ++ns) {
            v8s bw = *(const v8s*)(Wb + (size_t)(n0 + ns * 16 + l15) * EMB + k + l4 * 8);
            c[ns] = __builtin_amdgcn_mfma_f32_16x16x32_bf16(a, bw, c[ns], 0, 0, 0);
        }
    }
    #pragma unroll
    for (int ns = 0; ns < 4; ++ns) {
        const float bv = bias[n0 + ns * 16 + l15];
        #pragma unroll
        for (int r = 0; r < 4; ++r)
            out[(size_t)(m0 + l4 * 4 + r) * EMB + n0 + ns * 16 + l15] = c[ns][r] + bv;
    }
}

extern "C" void kernel_launch(void* const* d_in, const int* in_sizes, int n_in,
                              void* d_out, int out_size, void* d_ws, size_t ws_size,
                              hipStream_t stream)
{
    (void)in_sizes; (void)n_in; (void)out_size; (void)ws_size;
    const float* q   = (const float*)d_in[0];
    const float* k   = (const float*)d_in[1];
    const float* v   = (const float*)d_in[2];
    const float* Wq  = (const float*)d_in[3];
    const float* Wk  = (const float*)d_in[4];
    const float* Wv  = (const float*)d_in[5];
    const float* Wfc = (const float*)d_in[6];
    const float* bfc = (const float*)d_in[7];

    char* w = (char*)d_ws;
    unsigned short* Qp = (unsigned short*)(w);                      //  8 MiB
    unsigned short* Kp = (unsigned short*)(w + (8u  << 20));        //  8 MiB
    unsigned short* Vp = (unsigned short*)(w + (16u << 20));        //  8 MiB
    unsigned short* Vt = (unsigned short*)(w + (24u << 20));        //  8 MiB
    unsigned short* AO = (unsigned short*)(w + (32u << 20));        //  8 MiB
    unsigned short* Wb = (unsigned short*)(w + (40u << 20));        //  2 MiB
    unsigned short* Op = (unsigned short*)(w + (42u << 20));        // 16 MiB (2 halves)

    k_proj     <<<dim3(4096),      dim3(256),  0, stream>>>(q, k, v, Wq, Wk, Wv, Qp, Kp, Vp);
    k_transpose<<<dim3(16, 32),    dim3(256),  0, stream>>>(Vp, Vt);
    k_cvtw     <<<dim3(1024),      dim3(256),  0, stream>>>(Wfc, Wb);
    k_fattn    <<<dim3(64, 2, 2),  dim3(1024), 0, stream>>>(Qp, Kp, Vt, Op);
    k_merge    <<<dim3(2048),      dim3(256),  0, stream>>>(Op, AO);
    k_fc       <<<dim3(64, 16),    dim3(256),  0, stream>>>(AO, Wb, bfc, (float*)d_out);
}

// Round 5
// 346.690 us; speedup vs baseline: 1.4250x; 1.1500x over previous
//
#include <hip/hip_runtime.h>

#define S_LEN 2048
#define NHEAD 16
#define HDIM 64
#define EMB 1024

typedef short v8s __attribute__((ext_vector_type(8)));
typedef float v4f __attribute__((ext_vector_type(4)));

__device__ __forceinline__ unsigned short f2bf(float f) {
    union { float f; unsigned u; } v; v.f = f;
    unsigned r = v.u + 0x7FFFu + ((v.u >> 16) & 1u);
    return (unsigned short)(r >> 16);
}
__device__ __forceinline__ float bflo(unsigned u) {
    union { unsigned u; float f; } v; v.u = u << 16; return v.f;
}
__device__ __forceinline__ float bfhi(unsigned u) {
    union { unsigned u; float f; } v; v.u = u & 0xFFFF0000u; return v.f;
}
__device__ __forceinline__ unsigned pack2(float lo, float hi) {
    return (unsigned)f2bf(lo) | ((unsigned)f2bf(hi) << 16);
}
__device__ __forceinline__ v8s cvt8(float4 a, float4 b) {
    v8s r;
    ((unsigned*)&r)[0] = pack2(a.x, a.y);
    ((unsigned*)&r)[1] = pack2(a.z, a.w);
    ((unsigned*)&r)[2] = pack2(b.x, b.y);
    ((unsigned*)&r)[3] = pack2(b.z, b.w);
    return r;
}

// ---------------------------------------------------------------------------
// K1: MFMA projections. Grid (128 s-tiles of 32, 3 tensors), block = 2 waves.
// Each wave: 16 s-rows x all 16 heads. Q/K: D = x @ W^T -> Qp/Kp [b][h][s][d].
// V: D = W @ x^T -> Vt [b][h][d][s] (transposed at no extra cost).
// ---------------------------------------------------------------------------
__global__ __launch_bounds__(128) void k_proj2(
    const float* __restrict__ q, const float* __restrict__ k, const float* __restrict__ v,
    const float* __restrict__ Wq, const float* __restrict__ Wk, const float* __restrict__ Wv,
    unsigned short* __restrict__ Qp, unsigned short* __restrict__ Kp, unsigned short* __restrict__ Vt)
{
    const int t = threadIdx.x, wave = t >> 6, lane = t & 63;
    const int l15 = lane & 15, l4 = lane >> 4;
    const int mtx = blockIdx.y;                  // 0:q 1:k 2:v
    const int row0 = blockIdx.x * 32 + wave * 16;  // global row in [0,4096)
    const int b = row0 >> 11, s0 = row0 & 2047;
    const float* X = (mtx == 0) ? q : (mtx == 1) ? k : v;
    const float* W = (mtx == 0) ? Wq : (mtx == 1) ? Wk : Wv;

    // W fragments, wf[tile][c2] = W[tile*16+l15][c2*32 + l4*8 .. +7] (bf16).
    // Serves as B-frag (Q/K: B[k][n]=W[n][k]) and A-frag (V: A[m][k]=W[m][k]).
    v8s wf[4][2];
    #pragma unroll
    for (int tile = 0; tile < 4; ++tile)
        #pragma unroll
        for (int c2 = 0; c2 < 2; ++c2) {
            const float* wp = W + (tile * 16 + l15) * 64 + c2 * 32 + l4 * 8;
            wf[tile][c2] = cvt8(*(const float4*)wp, *(const float4*)(wp + 4));
        }

    for (int h = 0; h < NHEAD; ++h) {
        v8s xf[2];
        #pragma unroll
        for (int c2 = 0; c2 < 2; ++c2) {
            const float* xp = X + (size_t)(row0 + l15) * EMB + h * 64 + c2 * 32 + l4 * 8;
            xf[c2] = cvt8(*(const float4*)xp, *(const float4*)(xp + 4));
        }
        v4f acc[4];
        #pragma unroll
        for (int i = 0; i < 4; ++i) acc[i] = (v4f){0.f, 0.f, 0.f, 0.f};
        if (mtx < 2) {
            // D[m=s 16][n=e 64]
            #pragma unroll
            for (int ns = 0; ns < 4; ++ns)
                #pragma unroll
                for (int c2 = 0; c2 < 2; ++c2)
                    acc[ns] = __builtin_amdgcn_mfma_f32_16x16x32_bf16(xf[c2], wf[ns][c2], acc[ns], 0, 0, 0);
            unsigned short* dst = ((mtx == 0) ? Qp : Kp) + (size_t)(b * NHEAD + h) * S_LEN * HDIM;
            #pragma unroll
            for (int ns = 0; ns < 4; ++ns)
                #pragma unroll
                for (int r = 0; r < 4; ++r)
                    dst[(size_t)(s0 + l4 * 4 + r) * HDIM + ns * 16 + l15] = f2bf(acc[ns][r]);
        } else {
            // D[m=e 64][n=s 16]  (transposed V)
            #pragma unroll
            for (int ms = 0; ms < 4; ++ms)
                #pragma unroll
                for (int c2 = 0; c2 < 2; ++c2)
                    acc[ms] = __builtin_amdgcn_mfma_f32_16x16x32_bf16(wf[ms][c2], xf[c2], acc[ms], 0, 0, 0);
            unsigned short* dst = Vt + (size_t)(b * NHEAD + h) * HDIM * S_LEN;
            #pragma unroll
            for (int ms = 0; ms < 4; ++ms)
                #pragma unroll
                for (int r = 0; r < 4; ++r)
                    dst[(size_t)(ms * 16 + l4 * 4 + r) * S_LEN + s0 + l15] = f2bf(acc[ms][r]);
        }
    }
}

// ---------------------------------------------------------------------------
// K1c: W_fc fp32 -> bf16
// ---------------------------------------------------------------------------
__global__ __launch_bounds__(256) void k_cvtw(
    const float* __restrict__ W, unsigned short* __restrict__ Wb)
{
    const int i = (blockIdx.x * 256 + threadIdx.x) * 4;
    float4 wv = *(const float4*)(W + i);
    uint2 pk;
    pk.x = pack2(wv.x, wv.y);
    pk.y = pack2(wv.z, wv.w);
    *(uint2*)(Wb + i) = pk;
}

// ---------------------------------------------------------------------------
// K2: fused attention. One block = all 16 heads (wave w = head w) x 32 q rows
// x 1024-wide k-half. XCD-aware 1D swizzle: blockIdx%8 selects the (khalf,b)
// combo so each XCD pair's L2 caches one 4 MB K/V working set.
// ---------------------------------------------------------------------------
__global__ __launch_bounds__(1024, 4) void k_fattn(
    const unsigned short* __restrict__ Qp, const unsigned short* __restrict__ Kp,
    const unsigned short* __restrict__ Vt, unsigned short* __restrict__ Op)
{
    __shared__ unsigned short Pex[2][16][32][72];   // 144 KiB (double buffer)
    __shared__ float Zrs[32][68];                   // 8.5 KiB
    const int t = threadIdx.x, wave = t >> 6, lane = t & 63;
    const int l15 = lane & 15, l4 = lane >> 4;
    const int h = wave;
    const int id = blockIdx.x;
    const int slot = id & 7;          // -> XCD (round-robin heuristic)
    const int khalf = slot >> 2;      // combo = slot>>1 = {khalf,b}
    const int b = (slot >> 1) & 1;
    const int q0 = ((id >> 3) * 2 + (slot & 1)) * 32;
    const unsigned short* qh = Qp + (size_t)(b * NHEAD + h) * S_LEN * HDIM;
    const unsigned short* kh = Kp + (size_t)(b * NHEAD + h) * S_LEN * HDIM;
    const unsigned short* vh = Vt + (size_t)(b * NHEAD + h) * HDIM * S_LEN;

    v8s aq[2][2];
    #pragma unroll
    for (int qs = 0; qs < 2; ++qs)
        #pragma unroll
        for (int c2 = 0; c2 < 2; ++c2)
            aq[qs][c2] = *(const v8s*)(qh + (size_t)(q0 + qs * 16 + l15) * HDIM + c2 * 32 + l4 * 8);

    v4f o[2][4];
    #pragma unroll
    for (int qs = 0; qs < 2; ++qs)
        #pragma unroll
        for (int ds = 0; ds < 4; ++ds)
            o[qs][ds] = (v4f){0.f, 0.f, 0.f, 0.f};

    const int zq = t >> 5;         // 0..31: q row for Z-reduce
    const int zk = (t & 31) * 2;   // 0..62: k pair for Z-reduce

    for (int c = 0; c < 16; ++c) {
        const int kk0 = khalf * 1024 + c * 64;
        const int buf = c & 1;
        // ---- phase 1: S = Q K^T, exp to LDS ----
        #pragma unroll
        for (int ks = 0; ks < 4; ++ks) {
            const unsigned short* kb = kh + (size_t)(kk0 + ks * 16 + l15) * HDIM + l4 * 8;
            v8s b0 = *(const v8s*)kb;
            v8s b1 = *(const v8s*)(kb + 32);
            #pragma unroll
            for (int qs = 0; qs < 2; ++qs) {
                v4f sf = (v4f){0.f, 0.f, 0.f, 0.f};
                sf = __builtin_amdgcn_mfma_f32_16x16x32_bf16(aq[qs][0], b0, sf, 0, 0, 0);
                sf = __builtin_amdgcn_mfma_f32_16x16x32_bf16(aq[qs][1], b1, sf, 0, 0, 0);
                #pragma unroll
                for (int r = 0; r < 4; ++r)
                    Pex[buf][h][qs * 16 + l4 * 4 + r][ks * 16 + l15] =
                        f2bf(__expf(sf[r] * 0.03125f));
            }
        }
        __syncthreads();
        // ---- phase 2: Z over heads; Zr = 1/Z ----
        {
            float z0 = 0.f, z1 = 0.f;
            #pragma unroll
            for (int hh = 0; hh < 16; ++hh) {
                unsigned u = *(const unsigned*)&Pex[buf][hh][zq][zk];
                z0 += bflo(u); z1 += bfhi(u);
            }
            float2 zr;
            zr.x = __builtin_amdgcn_rcpf(z0);
            zr.y = __builtin_amdgcn_rcpf(z1);
            *(float2*)&Zrs[zq][zk] = zr;
        }
        __syncthreads();
        // ---- phase 3: normalize P (A-frag order) + PV MFMA ----
        #pragma unroll
        for (int kq = 0; kq < 2; ++kq) {
            v8s bv[4];
            #pragma unroll
            for (int ds = 0; ds < 4; ++ds)
                bv[ds] = *(const v8s*)(vh + (size_t)(ds * 16 + l15) * S_LEN + kk0 + kq * 32 + l4 * 8);
            #pragma unroll
            for (int qs = 0; qs < 2; ++qs) {
                uint4 pu = *(const uint4*)&Pex[buf][h][qs * 16 + l15][kq * 32 + l4 * 8];
                float4 za = *(const float4*)&Zrs[qs * 16 + l15][kq * 32 + l4 * 8];
                float4 zb = *(const float4*)&Zrs[qs * 16 + l15][kq * 32 + l4 * 8 + 4];
                unsigned pw[4];
                pw[0] = pack2(bflo(pu.x) * za.x, bfhi(pu.x) * za.y);
                pw[1] = pack2(bflo(pu.y) * za.z, bfhi(pu.y) * za.w);
                pw[2] = pack2(bflo(pu.z) * zb.x, bfhi(pu.z) * zb.y);
                pw[3] = pack2(bflo(pu.w) * zb.z, bfhi(pu.w) * zb.w);
                v8s pn;
                ((unsigned*)&pn)[0] = pw[0]; ((unsigned*)&pn)[1] = pw[1];
                ((unsigned*)&pn)[2] = pw[2]; ((unsigned*)&pn)[3] = pw[3];
                #pragma unroll
                for (int ds = 0; ds < 4; ++ds)
                    o[qs][ds] = __builtin_amdgcn_mfma_f32_16x16x32_bf16(pn, bv[ds], o[qs][ds], 0, 0, 0);
            }
        }
    }

    // partial O for this k-half, bf16, layout [khalf*2+b][s][e]
    unsigned short* op = Op + ((size_t)(khalf * 2 + b) * S_LEN) * EMB;
    #pragma unroll
    for (int qs = 0; qs < 2; ++qs)
        #pragma unroll
        for (int ds = 0; ds < 4; ++ds)
            #pragma unroll
            for (int r = 0; r < 4; ++r)
                op[(size_t)(q0 + qs * 16 + l4 * 4 + r) * EMB + h * 64 + ds * 16 + l15] =
                    f2bf(o[qs][ds][r]);
}

// ---------------------------------------------------------------------------
// K4: out = (Op0 + Op1) @ W_fc^T + b_fc  (merge folded into A-frag load)
// ---------------------------------------------------------------------------
__global__ __launch_bounds__(256) void k_fc(
    const unsigned short* __restrict__ Op, const unsigned short* __restrict__ Wb,
    const float* __restrict__ bias, float* __restrict__ out)
{
    const int t = threadIdx.x, wave = t >> 6, lane = t & 63;
    const int l15 = lane & 15, l4 = lane >> 4;
    const int m0 = blockIdx.x * 64 + wave * 16;
    const int n0 = blockIdx.y * 64;
    const int b = m0 >> 11, sr = m0 & 2047;
    const unsigned short* A0 = Op + ((size_t)(b)     * S_LEN) * EMB + (size_t)(sr + l15) * EMB;
    const unsigned short* A1 = Op + ((size_t)(2 + b) * S_LEN) * EMB + (size_t)(sr + l15) * EMB;
    v4f c[4];
    #pragma unroll
    for (int i = 0; i < 4; ++i) c[i] = (v4f){0.f, 0.f, 0.f, 0.f};
    for (int k = 0; k < EMB; k += 32) {
        uint4 u0 = *(const uint4*)(A0 + k + l4 * 8);
        uint4 u1 = *(const uint4*)(A1 + k + l4 * 8);
        v8s a;
        ((unsigned*)&a)[0] = pack2(bflo(u0.x) + bflo(u1.x), bfhi(u0.x) + bfhi(u1.x));
        ((unsigned*)&a)[1] = pack2(bflo(u0.y) + bflo(u1.y), bfhi(u0.y) + bfhi(u1.y));
        ((unsigned*)&a)[2] = pack2(bflo(u0.z) + bflo(u1.z), bfhi(u0.z) + bfhi(u1.z));
        ((unsigned*)&a)[3] = pack2(bflo(u0.w) + bflo(u1.w), bfhi(u0.w) + bfhi(u1.w));
        #pragma unroll
        for (int ns = 0; ns < 4; ++ns) {
            v8s bw = *(const v8s*)(Wb + (size_t)(n0 + ns * 16 + l15) * EMB + k + l4 * 8);
            c[ns] = __builtin_amdgcn_mfma_f32_16x16x32_bf16(a, bw, c[ns], 0, 0, 0);
        }
    }
    #pragma unroll
    for (int ns = 0; ns < 4; ++ns) {
        const float bv = bias[n0 + ns * 16 + l15];
        #pragma unroll
        for (int r = 0; r < 4; ++r)
            out[(size_t)(m0 + l4 * 4 + r) * EMB + n0 + ns * 16 + l15] = c[ns][r] + bv;
    }
}

extern "C" void kernel_launch(void* const* d_in, const int* in_sizes, int n_in,
                              void* d_out, int out_size, void* d_ws, size_t ws_size,
                              hipStream_t stream)
{
    (void)in_sizes; (void)n_in; (void)out_size; (void)ws_size;
    const float* q   = (const float*)d_in[0];
    const float* k   = (const float*)d_in[1];
    const float* v   = (const float*)d_in[2];
    const float* Wq  = (const float*)d_in[3];
    const float* Wk  = (const float*)d_in[4];
    const float* Wv  = (const float*)d_in[5];
    const float* Wfc = (const float*)d_in[6];
    const float* bfc = (const float*)d_in[7];

    char* w = (char*)d_ws;
    unsigned short* Qp = (unsigned short*)(w);                      //  8 MiB
    unsigned short* Kp = (unsigned short*)(w + (8u  << 20));        //  8 MiB
    unsigned short* Vt = (unsigned short*)(w + (16u << 20));        //  8 MiB
    unsigned short* Wb = (unsigned short*)(w + (24u << 20));        //  2 MiB
    unsigned short* Op = (unsigned short*)(w + (26u << 20));        // 16 MiB (2 halves)

    k_proj2 <<<dim3(128, 3), dim3(128),  0, stream>>>(q, k, v, Wq, Wk, Wv, Qp, Kp, Vt);
    k_cvtw  <<<dim3(1024),   dim3(256),  0, stream>>>(Wfc, Wb);
    k_fattn <<<dim3(256),    dim3(1024), 0, stream>>>(Qp, Kp, Vt, Op);
    k_fc    <<<dim3(64, 16), dim3(256),  0, stream>>>(Op, Wb, bfc, (float*)d_out);
}